// Round 1
// baseline (371.606 us; speedup 1.0000x reference)
//
#include <hip/hip_runtime.h>
#include <math.h>

// Problem constants (fixed by reference setup_inputs)
#define NQ    2048      // B*QB
#define Dd    256
#define NHh   8
#define HDd   32
#define KK    164       // 9+25+49+81
#define PPB   5440      // valid cells per batch: 64+256+1024+4096
#define M_TOT 21760     // 4 * PPB
#define TWO_D 512

// level bases within a batch's compacted KV
// l0:[0,64) S=8, l1:[64,320) S=16, l2:[320,1344) S=32, l3:[1344,5440) S=64

// ---------------------------------------------------------------------------
// Kernel 1: KV = fmap(valid cells) @ Wkv   (fp32 tiled GEMM, M=21760,N=512,K=256)
// ---------------------------------------------------------------------------
#define BM 128
#define BN 128
#define KT 16

__global__ __launch_bounds__(256) void kv_gemm(const float* __restrict__ fmap,
                                               const float* __restrict__ Wkv,
                                               float* __restrict__ kvws) {
    __shared__ float As[KT][BM + 4];
    __shared__ float Bs[KT][BN + 4];
    __shared__ int   rowOff[BM];

    const int t  = threadIdx.x;
    const int bm = blockIdx.x * BM;
    const int n0 = blockIdx.y * BN;

    if (t < BM) {
        int m = bm + t;
        int b = m / PPB;
        int r = m - b * PPB;
        int l, S, base, lg;
        if      (r < 64)   { l = 0; S = 8;  base = 0;    lg = 3; }
        else if (r < 320)  { l = 1; S = 16; base = 64;   lg = 4; }
        else if (r < 1344) { l = 2; S = 32; base = 320;  lg = 5; }
        else               { l = 3; S = 64; base = 1344; lg = 6; }
        int idx = r - base;
        int i = idx >> lg;
        int j = idx & (S - 1);
        rowOff[t] = ((b * 64 + i) * 64 + j) * 1024 + l * 256;  // fmap element offset
    }
    __syncthreads();

    const int tx = t & 15, ty = t >> 4;
    float acc[8][8];
#pragma unroll
    for (int i = 0; i < 8; i++)
#pragma unroll
        for (int j = 0; j < 8; j++) acc[i][j] = 0.f;

    for (int k0 = 0; k0 < Dd; k0 += KT) {
        // stage A tile (128 rows x 16 k), transposed into As[k][row]
#pragma unroll
        for (int s = 0; s < 2; s++) {
            int task = t + s * 256;           // 0..511
            int row  = task >> 2;
            int k4   = (task & 3) * 4;
            const float4 v = *(const float4*)(fmap + rowOff[row] + k0 + k4);
            As[k4 + 0][row] = v.x;
            As[k4 + 1][row] = v.y;
            As[k4 + 2][row] = v.z;
            As[k4 + 3][row] = v.w;
        }
        // stage B tile (16 k x 128 n)
#pragma unroll
        for (int s = 0; s < 2; s++) {
            int task = t + s * 256;
            int kk   = task >> 5;
            int c4   = (task & 31) * 4;
            *(float4*)(&Bs[kk][c4]) = *(const float4*)(Wkv + (k0 + kk) * TWO_D + n0 + c4);
        }
        __syncthreads();
#pragma unroll
        for (int kk = 0; kk < KT; kk++) {
            float a[8], bb[8];
#pragma unroll
            for (int i = 0; i < 8; i++) a[i]  = As[kk][ty * 8 + i];
#pragma unroll
            for (int j = 0; j < 8; j++) bb[j] = Bs[kk][tx * 8 + j];
#pragma unroll
            for (int i = 0; i < 8; i++)
#pragma unroll
                for (int j = 0; j < 8; j++)
                    acc[i][j] = fmaf(a[i], bb[j], acc[i][j]);
        }
        __syncthreads();
    }

#pragma unroll
    for (int i = 0; i < 8; i++) {
        int m = bm + ty * 8 + i;
        float* dst = kvws + (size_t)m * TWO_D + n0 + tx * 8;
#pragma unroll
        for (int j = 0; j < 8; j += 4) {
            *(float4*)(dst + j) = make_float4(acc[i][j], acc[i][j + 1],
                                              acc[i][j + 2], acc[i][j + 3]);
        }
    }
}

// ---------------------------------------------------------------------------
// Kernel 2: in-place RoPE on the K half of kvws (key_pos is cell-determined)
// ---------------------------------------------------------------------------
__global__ __launch_bounds__(256) void rope_k(float* __restrict__ kvws,
                                              const float* __restrict__ freqs) {
    int gid = blockIdx.x * 256 + threadIdx.x;   // M_TOT * 128 pair-slots
    int m = gid >> 7;       // position
    int p = gid & 127;      // pair index within K half (8 heads x 16 freqs)
    int f = p & 15;

    int b = m / PPB;
    int r = m - b * PPB;
    int l, S, base, lg, inv;
    if      (r < 64)   { l = 0; S = 8;  base = 0;    lg = 3; inv = 8; }
    else if (r < 320)  { l = 1; S = 16; base = 64;   lg = 4; inv = 4; }
    else if (r < 1344) { l = 2; S = 32; base = 320;  lg = 5; inv = 2; }
    else               { l = 3; S = 64; base = 1344; lg = 6; inv = 1; }
    int idx = r - base;
    int i = idx >> lg;
    int j = idx & (S - 1);

    float px = (float)(i * inv), py = (float)(j * inv), pl = (float)l;
    float ang = px * freqs[f] + py * freqs[16 + f] + pl * freqs[32 + f];
    float c = cosf(ang), s = sinf(ang);

    float2* kp = (float2*)kvws + (size_t)m * 256 + p;  // K half = first 128 float2
    float2 v = *kp;
    *kp = make_float2(v.x * c - v.y * s, v.x * s + v.y * c);
}

// ---------------------------------------------------------------------------
// Kernel 3: per-query fused LN -> Wq -> RoPE(q) -> scores -> softmax -> PV -> Wout(+res)
// one block (256 threads) per query; thread t <-> (head h = t>>5, dim d = t&31)
// ---------------------------------------------------------------------------
__global__ __launch_bounds__(256) void attn_fused(const float* __restrict__ query,
                                                  const float* __restrict__ qpos,
                                                  const float* __restrict__ Wq,
                                                  const float* __restrict__ Wout,
                                                  const float* __restrict__ gamma,
                                                  const float* __restrict__ beta,
                                                  const float* __restrict__ freqs,
                                                  const float* __restrict__ kvws,
                                                  float* __restrict__ out) {
    __shared__ float qn[Dd];
    __shared__ float sL[NHh * KK];
    __shared__ int   kidx[KK];
    __shared__ float attnL[Dd];
    __shared__ float red[4];
    __shared__ float invS[NHh];

    const int q = blockIdx.x;
    const int t = threadIdx.x;
    const int wid = t >> 6;

    // ---- LayerNorm ----
    float x = query[q * Dd + t];
    float s = x;
#pragma unroll
    for (int mK = 32; mK >= 1; mK >>= 1) s += __shfl_xor(s, mK);
    if ((t & 63) == 0) red[wid] = s;
    __syncthreads();
    float mu = (red[0] + red[1] + red[2] + red[3]) * (1.0f / 256.0f);
    float dx = x - mu;
    float s2 = dx * dx;
#pragma unroll
    for (int mK = 32; mK >= 1; mK >>= 1) s2 += __shfl_xor(s2, mK);
    __syncthreads();
    if ((t & 63) == 0) red[wid] = s2;
    __syncthreads();
    float var = (red[0] + red[1] + red[2] + red[3]) * (1.0f / 256.0f);
    float rs = rsqrtf(var + 1e-5f);
    qn[t] = dx * rs * gamma[t] + beta[t];
    __syncthreads();

    // ---- q = qn @ Wq (column t) ----
    float acc = 0.f;
#pragma unroll 8
    for (int d = 0; d < Dd; d++) acc = fmaf(qn[d], Wq[d * Dd + t], acc);

    // ---- RoPE on q; pos = (qx, qy, 3.0) ----
    float qx = qpos[q * 4 + 1];
    float qy = qpos[q * 4 + 2];
    int   bb = (int)qpos[q * 4 + 0];
    {
        int f = (t & 31) >> 1;
        float ang = qx * freqs[f] + qy * freqs[16 + f] + 3.0f * freqs[32 + f];
        float c = cosf(ang), sn = sinf(ang);
        float partner = __shfl_xor(acc, 1);
        bool ev = !(t & 1);
        acc = ev ? (acc * c - partner * sn) : (partner * sn + acc * c);
    }
    float qr = acc;  // this thread's q[h, d] after RoPE

    // ---- neighbor indices ----
    if (t < KK) {
        int k = t;
        int S, base, off, sz, half, lg;
        if      (k < 9)  { S = 8;  base = 0;    off = k;      sz = 3; half = 1; lg = 3; }
        else if (k < 34) { S = 16; base = 64;   off = k - 9;  sz = 5; half = 2; lg = 4; }
        else if (k < 83) { S = 32; base = 320;  off = k - 34; sz = 7; half = 3; lg = 5; }
        else             { S = 64; base = 1344; off = k - 83; sz = 9; half = 4; lg = 6; }
        int di = off / sz - half;
        int dj = off % sz - half;
        float scal = (float)S * (1.0f / 64.0f);
        int ci = (int)floorf(qx * scal);
        int cj = (int)floorf(qy * scal);
        int i = ci + di, j = cj + dj;
        bool valid = (i >= 0) & (i < S) & (j >= 0) & (j < S);
        kidx[t] = valid ? (bb * PPB + base + (i << lg) + j) : -1;
    }
    __syncthreads();

    // ---- scores: s[h,k] = sum_d q[h,d] * K[kidx[k], h, d] ----
    const int h = t >> 5, lane = t & 31;
#pragma unroll 2
    for (int k = 0; k < KK; k++) {
        int ki = kidx[k];
        float kv = 0.f;
        if (ki >= 0) kv = kvws[(size_t)ki * TWO_D + t];
        float p = qr * kv;
        p += __shfl_xor(p, 16);
        p += __shfl_xor(p, 8);
        p += __shfl_xor(p, 4);
        p += __shfl_xor(p, 2);
        p += __shfl_xor(p, 1);
        if (lane == (k & 31)) sL[h * KK + k] = (ki >= 0) ? p : -INFINITY;
    }
    __syncthreads();

    // ---- softmax over k per head (32 lanes cooperate) ----
    float mx = -INFINITY;
    for (int k = lane; k < KK; k += 32) mx = fmaxf(mx, sL[h * KK + k]);
#pragma unroll
    for (int mK = 16; mK >= 1; mK >>= 1) mx = fmaxf(mx, __shfl_xor(mx, mK));
    float se = 0.f;
    for (int k = lane; k < KK; k += 32) {
        float e = expf(sL[h * KK + k] - mx);
        sL[h * KK + k] = e;
        se += e;
    }
#pragma unroll
    for (int mK = 16; mK >= 1; mK >>= 1) se += __shfl_xor(se, mK);
    if (lane == 0) invS[h] = 1.0f / se;
    __syncthreads();

    // ---- PV: out[h,d] = (1/se) * sum_k e[k] * V[kidx[k], h, d] ----
    float acc2 = 0.f;
#pragma unroll 2
    for (int k = 0; k < KK; k++) {
        int ki = kidx[k];
        if (ki >= 0) acc2 = fmaf(sL[h * KK + k], kvws[(size_t)ki * TWO_D + 256 + t], acc2);
    }
    attnL[t] = acc2 * invS[h];
    __syncthreads();

    // ---- out = attn @ Wout + residual ----
    float o = query[q * Dd + t];
#pragma unroll 8
    for (int d = 0; d < Dd; d++) o = fmaf(attnL[d], Wout[d * Dd + t], o);
    out[q * Dd + t] = o;
}

// ---------------------------------------------------------------------------
extern "C" void kernel_launch(void* const* d_in, const int* in_sizes, int n_in,
                              void* d_out, int out_size, void* d_ws, size_t ws_size,
                              hipStream_t stream) {
    const float* query = (const float*)d_in[0];
    const float* qpos  = (const float*)d_in[1];
    const float* fmap  = (const float*)d_in[3];
    const float* gamma = (const float*)d_in[5];
    const float* beta  = (const float*)d_in[6];
    const float* Wq    = (const float*)d_in[7];
    const float* Wkv   = (const float*)d_in[8];
    const float* Wout  = (const float*)d_in[9];
    const float* freqs = (const float*)d_in[10];
    float* out  = (float*)d_out;
    float* kvws = (float*)d_ws;   // 21760 * 512 * 4 B = 44.6 MB

    kv_gemm<<<dim3(M_TOT / BM, TWO_D / BN), 256, 0, stream>>>(fmap, Wkv, kvws);
    rope_k<<<dim3((M_TOT * 128) / 256), 256, 0, stream>>>(kvws, freqs);
    attn_fused<<<dim3(NQ), 256, 0, stream>>>(query, qpos, Wq, Wout, gamma, beta,
                                             freqs, kvws, out);
}

// Round 3
// 279.341 us; speedup vs baseline: 1.3303x; 1.3303x over previous
//
#include <hip/hip_runtime.h>
#include <math.h>

// Problem constants (fixed by reference setup_inputs)
#define NQ    2048      // B*QB
#define Dd    256
#define NHh   8
#define HDd   32
#define KK    164       // 9+25+49+81
#define PPB   5440      // valid cells per batch: 64+256+1024+4096
#define M_TOT 21760     // 4 * PPB
#define TWO_D 512

using bf16x8 = __attribute__((ext_vector_type(8))) short;
using f32x4  = __attribute__((ext_vector_type(4))) float;

__device__ __forceinline__ unsigned short bf16_rne(float x) {
    unsigned u = __float_as_uint(x);
    return (unsigned short)((u + 0x7fffu + ((u >> 16) & 1u)) >> 16);
}

__device__ __forceinline__ void gload_lds16(const void* g, void* s) {
    __builtin_amdgcn_global_load_lds(
        (const __attribute__((address_space(1))) void*)g,
        (__attribute__((address_space(3))) void*)s, 16, 0, 0);
}

// decompose compacted row index -> level geometry
__device__ __forceinline__ void row_geom(int r, int& l, int& S, int& base, int& lg, int& inv) {
    if      (r < 64)   { l = 0; S = 8;  base = 0;    lg = 3; inv = 8; }
    else if (r < 320)  { l = 1; S = 16; base = 64;   lg = 4; inv = 4; }
    else if (r < 1344) { l = 2; S = 32; base = 320;  lg = 5; inv = 2; }
    else               { l = 3; S = 64; base = 1344; lg = 6; inv = 1; }
}

// ---------------------------------------------------------------------------
// Kernel 0a: gather valid cells, split fp32 -> bf16 hi/lo, compacted [m][k]
// ---------------------------------------------------------------------------
__global__ __launch_bounds__(256) void gather_split(const float* __restrict__ fmap,
                                                    unsigned short* __restrict__ Ahi,
                                                    unsigned short* __restrict__ Alo) {
    int gid = blockIdx.x * 256 + threadIdx.x;   // m*64 + c4
    int m = gid >> 6, c4 = (gid & 63) << 2;
    int b = m / PPB, r = m - b * PPB;
    int l, S, base, lg, inv;
    row_geom(r, l, S, base, lg, inv);
    int idx = r - base;
    int i = idx >> lg, j = idx & (S - 1);
    size_t rowOff = ((size_t)((b * 64 + i) * 64 + j)) * 1024 + l * 256;
    const float4 v = *(const float4*)(fmap + rowOff + c4);
    ushort4 hi, lo;
    {
        hi.x = bf16_rne(v.x); lo.x = bf16_rne(v.x - __uint_as_float((unsigned)hi.x << 16));
        hi.y = bf16_rne(v.y); lo.y = bf16_rne(v.y - __uint_as_float((unsigned)hi.y << 16));
        hi.z = bf16_rne(v.z); lo.z = bf16_rne(v.z - __uint_as_float((unsigned)hi.z << 16));
        hi.w = bf16_rne(v.w); lo.w = bf16_rne(v.w - __uint_as_float((unsigned)hi.w << 16));
    }
    *(ushort4*)(Ahi + (size_t)m * 256 + c4) = hi;
    *(ushort4*)(Alo + (size_t)m * 256 + c4) = lo;
}

// ---------------------------------------------------------------------------
// Kernel 0b: Wkv (256x512, row-major k) -> Bt hi/lo transposed [n][k]
// ---------------------------------------------------------------------------
__global__ __launch_bounds__(256) void split_w(const float* __restrict__ Wkv,
                                               unsigned short* __restrict__ Bthi,
                                               unsigned short* __restrict__ Btlo) {
    int gid = blockIdx.x * 256 + threadIdx.x;   // 131072
    int k = gid & 255, n = gid >> 8;
    float x = Wkv[k * TWO_D + n];
    unsigned short h = bf16_rne(x);
    unsigned short lo = bf16_rne(x - __uint_as_float((unsigned)h << 16));
    Bthi[n * 256 + k] = h;
    Btlo[n * 256 + k] = lo;
}

// ---------------------------------------------------------------------------
// Kernel 1: KV = A @ Wkv via split-bf16 MFMA.
// C = Ahi*Bhi + Ahi*Blo + Alo*Bhi  ==  24 K-tiles of 32 (3 segments x 8).
// 128x128 tile, 4 waves (2x2), each wave 64x64 = 4x4 frags of 16x16x32.
// LDS [m][k] bf16, 16B-slot XOR swizzle (slot ^ (m&3)) via pre-swizzled
// global source for global_load_lds + swizzled ds_read.
// ---------------------------------------------------------------------------
__global__ __launch_bounds__(256) void kv_gemm_mfma(const unsigned short* __restrict__ Ahi,
                                                    const unsigned short* __restrict__ Alo,
                                                    const unsigned short* __restrict__ Bthi,
                                                    const unsigned short* __restrict__ Btlo,
                                                    float* __restrict__ kvws) {
    __shared__ __align__(16) short As[2][128 * 32];
    __shared__ __align__(16) short Bs[2][128 * 32];

    const int t  = threadIdx.x;
    const int w  = t >> 6, l = t & 63;
    const int wr = w >> 1, wc = w & 1;
    const int bm = blockIdx.x * 128, n0 = blockIdx.y * 128;
    const int lr = l & 15, ks = l >> 4;
    const int ksw8 = ((ks ^ (lr & 3)) << 3);     // swizzled k-slot, in elements

    f32x4 acc[4][4];
#pragma unroll
    for (int i = 0; i < 4; i++)
#pragma unroll
        for (int j = 0; j < 4; j++) {
            f32x4 z = {0.f, 0.f, 0.f, 0.f};
            acc[i][j] = z;
        }

    // staging lane geometry (per wave: 2 issues x 16 rows x 64B)
    const int srow = l >> 2;                      // 0..15
    const int sslot = l & 3;

    auto stage = [&](int kt, int buf) {
        int seg = kt >> 3;
        const unsigned short* Aseg = (seg < 2) ? Ahi : Alo;
        const unsigned short* Bseg = (seg == 1) ? Btlo : Bthi;
        size_t k0b = (size_t)((kt & 7) << 6);     // byte offset of k0 within row
#pragma unroll
        for (int i = 0; i < 2; i++) {
            int rb = w * 32 + i * 16;             // wave-uniform row base
            int m  = rb + srow;
            int gs = sslot ^ (m & 3);             // pre-swizzled global slot
            gload_lds16((const char*)Aseg + (((size_t)(bm + m)) << 9) + k0b + (gs << 4),
                        (void*)&As[buf][rb * 32]);
            gload_lds16((const char*)Bseg + (((size_t)(n0 + m)) << 9) + k0b + (gs << 4),
                        (void*)&Bs[buf][rb * 32]);
        }
    };

    stage(0, 0);
    __syncthreads();

    for (int kt = 0; kt < 24; kt++) {
        int cur = kt & 1;
        if (kt < 23) stage(kt + 1, cur ^ 1);

        bf16x8 afr[4], bfr[4];
#pragma unroll
        for (int f = 0; f < 4; f++) {
            int m = wr * 64 + f * 16 + lr;
            afr[f] = *(const bf16x8*)&As[cur][m * 32 + ksw8];
            int n = wc * 64 + f * 16 + lr;
            bfr[f] = *(const bf16x8*)&Bs[cur][n * 32 + ksw8];
        }
#pragma unroll
        for (int i = 0; i < 4; i++)
#pragma unroll
            for (int j = 0; j < 4; j++)
                acc[i][j] = __builtin_amdgcn_mfma_f32_16x16x32_bf16(afr[i], bfr[j],
                                                                    acc[i][j], 0, 0, 0);
        __syncthreads();
    }

    // epilogue: C/D layout col = lane&15, row = (lane>>4)*4 + reg
#pragma unroll
    for (int i = 0; i < 4; i++) {
        int mg = bm + wr * 64 + i * 16 + ks * 4;
#pragma unroll
        for (int j = 0; j < 4; j++) {
            int ng = n0 + wc * 64 + j * 16 + lr;
#pragma unroll
            for (int r = 0; r < 4; r++)
                kvws[(size_t)(mg + r) * TWO_D + ng] = acc[i][j][r];
        }
    }
}

// ---------------------------------------------------------------------------
// Kernel 1-fallback: fp32 VALU GEMM (round-1 version), used if ws too small
// ---------------------------------------------------------------------------
#define BM 128
#define BN 128
#define KT 16

__global__ __launch_bounds__(256) void kv_gemm(const float* __restrict__ fmap,
                                               const float* __restrict__ Wkv,
                                               float* __restrict__ kvws) {
    __shared__ float Asf[KT][BM + 4];
    __shared__ float Bsf[KT][BN + 4];
    __shared__ int   rowOff[BM];

    const int t  = threadIdx.x;
    const int bm = blockIdx.x * BM;
    const int n0 = blockIdx.y * BN;

    if (t < BM) {
        int m = bm + t;
        int b = m / PPB;
        int r = m - b * PPB;
        int l, S, base, lg, inv;
        row_geom(r, l, S, base, lg, inv);
        int idx = r - base;
        int i = idx >> lg;
        int j = idx & (S - 1);
        rowOff[t] = ((b * 64 + i) * 64 + j) * 1024 + l * 256;
    }
    __syncthreads();

    const int tx = t & 15, ty = t >> 4;
    float acc[8][8];
#pragma unroll
    for (int i = 0; i < 8; i++)
#pragma unroll
        for (int j = 0; j < 8; j++) acc[i][j] = 0.f;

    for (int k0 = 0; k0 < Dd; k0 += KT) {
#pragma unroll
        for (int s = 0; s < 2; s++) {
            int task = t + s * 256;
            int row  = task >> 2;
            int k4   = (task & 3) * 4;
            const float4 v = *(const float4*)(fmap + rowOff[row] + k0 + k4);
            Asf[k4 + 0][row] = v.x;
            Asf[k4 + 1][row] = v.y;
            Asf[k4 + 2][row] = v.z;
            Asf[k4 + 3][row] = v.w;
        }
#pragma unroll
        for (int s = 0; s < 2; s++) {
            int task = t + s * 256;
            int kk   = task >> 5;
            int c4   = (task & 31) * 4;
            *(float4*)(&Bsf[kk][c4]) = *(const float4*)(Wkv + (k0 + kk) * TWO_D + n0 + c4);
        }
        __syncthreads();
#pragma unroll
        for (int kk = 0; kk < KT; kk++) {
            float a[8], bb[8];
#pragma unroll
            for (int i = 0; i < 8; i++) a[i]  = Asf[kk][ty * 8 + i];
#pragma unroll
            for (int j = 0; j < 8; j++) bb[j] = Bsf[kk][tx * 8 + j];
#pragma unroll
            for (int i = 0; i < 8; i++)
#pragma unroll
                for (int j = 0; j < 8; j++)
                    acc[i][j] = fmaf(a[i], bb[j], acc[i][j]);
        }
        __syncthreads();
    }

#pragma unroll
    for (int i = 0; i < 8; i++) {
        int m = bm + ty * 8 + i;
        float* dst = kvws + (size_t)m * TWO_D + n0 + tx * 8;
#pragma unroll
        for (int j = 0; j < 8; j += 4) {
            *(float4*)(dst + j) = make_float4(acc[i][j], acc[i][j + 1],
                                              acc[i][j + 2], acc[i][j + 3]);
        }
    }
}

// ---------------------------------------------------------------------------
// Kernel 2: in-place RoPE on the K half of kvws (key_pos is cell-determined)
// ---------------------------------------------------------------------------
__global__ __launch_bounds__(256) void rope_k(float* __restrict__ kvws,
                                              const float* __restrict__ freqs) {
    int gid = blockIdx.x * 256 + threadIdx.x;   // M_TOT * 128 pair-slots
    int m = gid >> 7;       // position
    int p = gid & 127;      // pair index within K half (8 heads x 16 freqs)
    int f = p & 15;

    int b = m / PPB;
    int r = m - b * PPB;
    int l, S, base, lg, inv;
    row_geom(r, l, S, base, lg, inv);
    int idx = r - base;
    int i = idx >> lg;
    int j = idx & (S - 1);

    float px = (float)(i * inv), py = (float)(j * inv), pl = (float)l;
    float ang = px * freqs[f] + py * freqs[16 + f] + pl * freqs[32 + f];
    float c = cosf(ang), s = sinf(ang);

    float2* kp = (float2*)kvws + (size_t)m * 256 + p;  // K half = first 128 float2
    float2 v = *kp;
    *kp = make_float2(v.x * c - v.y * s, v.x * s + v.y * c);
}

// ---------------------------------------------------------------------------
// Kernel 3: per-query fused LN -> Wq -> RoPE(q) -> scores -> softmax -> PV -> Wout(+res)
// one block (256 threads) per query; thread t <-> (head h = t>>5, dim d = t&31)
// v2: scores via per-thread float4 dot (no shfl chain); ILP-4 GEMV chains;
//     branchless PV.
// ---------------------------------------------------------------------------
__global__ __launch_bounds__(256) void attn_fused(const float* __restrict__ query,
                                                  const float* __restrict__ qpos,
                                                  const float* __restrict__ Wq,
                                                  const float* __restrict__ Wout,
                                                  const float* __restrict__ gamma,
                                                  const float* __restrict__ beta,
                                                  const float* __restrict__ freqs,
                                                  const float* __restrict__ kvws,
                                                  float* __restrict__ out) {
    __shared__ float qn[Dd];
    __shared__ __align__(16) float qsh[Dd];
    __shared__ float sL[NHh * KK];
    __shared__ int   kidx[KK];
    __shared__ float attnL[Dd];
    __shared__ float red[4];
    __shared__ float invS[NHh];

    const int q = blockIdx.x;
    const int t = threadIdx.x;
    const int wid = t >> 6;
    const int h = t >> 5, lane = t & 31;

    // ---- LayerNorm ----
    float x = query[q * Dd + t];
    float s = x;
#pragma unroll
    for (int mK = 32; mK >= 1; mK >>= 1) s += __shfl_xor(s, mK);
    if ((t & 63) == 0) red[wid] = s;
    __syncthreads();
    float mu = (red[0] + red[1] + red[2] + red[3]) * (1.0f / 256.0f);
    float dx = x - mu;
    float s2 = dx * dx;
#pragma unroll
    for (int mK = 32; mK >= 1; mK >>= 1) s2 += __shfl_xor(s2, mK);
    __syncthreads();
    if ((t & 63) == 0) red[wid] = s2;
    __syncthreads();
    float var = (red[0] + red[1] + red[2] + red[3]) * (1.0f / 256.0f);
    float rs = rsqrtf(var + 1e-5f);
    qn[t] = dx * rs * gamma[t] + beta[t];
    __syncthreads();

    // ---- q = qn @ Wq (column t), ILP-4 ----
    float a0 = 0.f, a1 = 0.f, a2 = 0.f, a3 = 0.f;
#pragma unroll 8
    for (int d = 0; d < Dd; d += 4) {
        a0 = fmaf(qn[d + 0], Wq[(d + 0) * Dd + t], a0);
        a1 = fmaf(qn[d + 1], Wq[(d + 1) * Dd + t], a1);
        a2 = fmaf(qn[d + 2], Wq[(d + 2) * Dd + t], a2);
        a3 = fmaf(qn[d + 3], Wq[(d + 3) * Dd + t], a3);
    }
    float acc = (a0 + a1) + (a2 + a3);

    // ---- RoPE on q; pos = (qx, qy, 3.0) ----
    float qx = qpos[q * 4 + 1];
    float qy = qpos[q * 4 + 2];
    int   bb = (int)qpos[q * 4 + 0];
    {
        int f = (t & 31) >> 1;
        float ang = qx * freqs[f] + qy * freqs[16 + f] + 3.0f * freqs[32 + f];
        float c = cosf(ang), sn = sinf(ang);
        float partner = __shfl_xor(acc, 1);
        bool ev = !(t & 1);
        acc = ev ? (acc * c - partner * sn) : (partner * sn + acc * c);
    }
    qsh[t] = acc;   // q[h, d] after RoPE

    // ---- neighbor indices ----
    if (t < KK) {
        int k = t;
        int S, base, off, sz, half, lg;
        if      (k < 9)  { S = 8;  base = 0;    off = k;      sz = 3; half = 1; lg = 3; }
        else if (k < 34) { S = 16; base = 64;   off = k - 9;  sz = 5; half = 2; lg = 4; }
        else if (k < 83) { S = 32; base = 320;  off = k - 34; sz = 7; half = 3; lg = 5; }
        else             { S = 64; base = 1344; off = k - 83; sz = 9; half = 4; lg = 6; }
        int di = off / sz - half;
        int dj = off % sz - half;
        float scal = (float)S * (1.0f / 64.0f);
        int ci = (int)floorf(qx * scal);
        int cj = (int)floorf(qy * scal);
        int i = ci + di, j = cj + dj;
        bool valid = (i >= 0) & (i < S) & (j >= 0) & (j < S);
        kidx[t] = valid ? (bb * PPB + base + (i << lg) + j) : -1;
    }
    __syncthreads();

    // ---- scores: thread (h, lane) computes full 32-dot from global (8x float4) ----
    float4 qv[8];
    {
        const float4* qp = (const float4*)(qsh + h * HDd);
#pragma unroll
        for (int i = 0; i < 8; i++) qv[i] = qp[i];
    }
#pragma unroll
    for (int ct = 0; ct < 6; ++ct) {
        int k = ct * 32 + lane;
        if (k >= KK) break;                   // only tail tile diverges
        int ki = kidx[k];
        int kr = ki < 0 ? 0 : ki;
        const float4* kp = (const float4*)(kvws + (size_t)kr * TWO_D + h * HDd);
        float c0 = 0.f, c1 = 0.f;
#pragma unroll
        for (int i = 0; i < 8; i += 2) {
            float4 k0v = kp[i], k1v = kp[i + 1];
            c0 = fmaf(qv[i].x, k0v.x, c0); c0 = fmaf(qv[i].y, k0v.y, c0);
            c0 = fmaf(qv[i].z, k0v.z, c0); c0 = fmaf(qv[i].w, k0v.w, c0);
            c1 = fmaf(qv[i + 1].x, k1v.x, c1); c1 = fmaf(qv[i + 1].y, k1v.y, c1);
            c1 = fmaf(qv[i + 1].z, k1v.z, c1); c1 = fmaf(qv[i + 1].w, k1v.w, c1);
        }
        sL[h * KK + k] = (ki >= 0) ? (c0 + c1) : -INFINITY;
    }
    __syncthreads();

    // ---- softmax over k per head (32 lanes cooperate) ----
    float mx = -INFINITY;
    for (int k = lane; k < KK; k += 32) mx = fmaxf(mx, sL[h * KK + k]);
#pragma unroll
    for (int mK = 16; mK >= 1; mK >>= 1) mx = fmaxf(mx, __shfl_xor(mx, mK));
    float se = 0.f;
    for (int k = lane; k < KK; k += 32) {
        float e = expf(sL[h * KK + k] - mx);
        sL[h * KK + k] = e;
        se += e;
    }
#pragma unroll
    for (int mK = 16; mK >= 1; mK >>= 1) se += __shfl_xor(se, mK);
    if (lane == 0) invS[h] = 1.0f / se;
    __syncthreads();

    // ---- PV: out[h,d] = (1/se) * sum_k e[k] * V[kidx[k], h, d]  (branchless) ----
    float p0 = 0.f, p1 = 0.f, p2 = 0.f, p3 = 0.f;
#pragma unroll 4
    for (int k = 0; k < 164; k += 4) {
        int ki0 = kidx[k],     kr0 = ki0 < 0 ? 0 : ki0;
        int ki1 = kidx[k + 1], kr1 = ki1 < 0 ? 0 : ki1;
        int ki2 = kidx[k + 2], kr2 = ki2 < 0 ? 0 : ki2;
        int ki3 = kidx[k + 3], kr3 = ki3 < 0 ? 0 : ki3;
        p0 = fmaf(sL[h * KK + k],     kvws[(size_t)kr0 * TWO_D + Dd + t], p0);
        p1 = fmaf(sL[h * KK + k + 1], kvws[(size_t)kr1 * TWO_D + Dd + t], p1);
        p2 = fmaf(sL[h * KK + k + 2], kvws[(size_t)kr2 * TWO_D + Dd + t], p2);
        p3 = fmaf(sL[h * KK + k + 3], kvws[(size_t)kr3 * TWO_D + Dd + t], p3);
    }
    attnL[t] = ((p0 + p1) + (p2 + p3)) * invS[h];
    __syncthreads();

    // ---- out = attn @ Wout + residual, ILP-4 ----
    float o0 = query[q * Dd + t], o1 = 0.f, o2 = 0.f, o3 = 0.f;
#pragma unroll 8
    for (int d = 0; d < Dd; d += 4) {
        o0 = fmaf(attnL[d + 0], Wout[(d + 0) * Dd + t], o0);
        o1 = fmaf(attnL[d + 1], Wout[(d + 1) * Dd + t], o1);
        o2 = fmaf(attnL[d + 2], Wout[(d + 2) * Dd + t], o2);
        o3 = fmaf(attnL[d + 3], Wout[(d + 3) * Dd + t], o3);
    }
    out[q * Dd + t] = (o0 + o1) + (o2 + o3);
}

// ---------------------------------------------------------------------------
extern "C" void kernel_launch(void* const* d_in, const int* in_sizes, int n_in,
                              void* d_out, int out_size, void* d_ws, size_t ws_size,
                              hipStream_t stream) {
    const float* query = (const float*)d_in[0];
    const float* qpos  = (const float*)d_in[1];
    const float* fmap  = (const float*)d_in[3];
    const float* gamma = (const float*)d_in[5];
    const float* beta  = (const float*)d_in[6];
    const float* Wq    = (const float*)d_in[7];
    const float* Wkv   = (const float*)d_in[8];
    const float* Wout  = (const float*)d_in[9];
    const float* freqs = (const float*)d_in[10];
    float* out  = (float*)d_out;
    float* kvws = (float*)d_ws;                 // 21760*512*4 = 44,564,480 B

    const size_t KV_B  = (size_t)M_TOT * TWO_D * 4;        // 44,564,480
    const size_t A_B   = (size_t)M_TOT * Dd * 2;           // 11,141,120
    const size_t W_B   = (size_t)Dd * TWO_D;               // 131,072 elems -> *2 B below
    const size_t need  = KV_B + 2 * A_B + 2 * (W_B * 2);   // 67,371,008

    if (ws_size >= need) {
        unsigned short* Ahi  = (unsigned short*)((char*)d_ws + KV_B);
        unsigned short* Alo  = (unsigned short*)((char*)d_ws + KV_B + A_B);
        unsigned short* Bthi = (unsigned short*)((char*)d_ws + KV_B + 2 * A_B);
        unsigned short* Btlo = (unsigned short*)((char*)d_ws + KV_B + 2 * A_B + W_B * 2);

        gather_split<<<dim3((M_TOT * 64) / 256), 256, 0, stream>>>(fmap, Ahi, Alo);
        split_w<<<dim3((Dd * TWO_D) / 256), 256, 0, stream>>>(Wkv, Bthi, Btlo);
        kv_gemm_mfma<<<dim3(M_TOT / 128, TWO_D / 128), 256, 0, stream>>>(Ahi, Alo, Bthi, Btlo, kvws);
    } else {
        kv_gemm<<<dim3(M_TOT / BM, TWO_D / BN), 256, 0, stream>>>(fmap, Wkv, kvws);
    }
    rope_k<<<dim3((M_TOT * 128) / 256), 256, 0, stream>>>(kvws, freqs);
    attn_fused<<<dim3(NQ), 256, 0, stream>>>(query, qpos, Wq, Wout, gamma, beta,
                                             freqs, kvws, out);
}